// Round 10
// baseline (479.715 us; speedup 1.0000x reference)
//
#include <hip/hip_runtime.h>

#define NN 100000
#define EE 1600000
#define HN 128
#define OO 64
#define SB 256     // stats blocks
#define NBUCK 196  // ceil(NN/512), bucket = row >> 9
#define CH 4096    // edges per bucketing chunk
#define SLAB 16384 // fixed slab per bucket (mean 8192, +90 sigma safe)

typedef __attribute__((ext_vector_type(8))) short bf16x8;
typedef __attribute__((ext_vector_type(4))) float f32x4;

__device__ __forceinline__ unsigned short f2bf(float f){ // RNE bf16
  unsigned u = __float_as_uint(f);
  return (unsigned short)((u + 0x7FFFu + ((u >> 16) & 1u)) >> 16);
}
__device__ __forceinline__ float bflo(unsigned u){ return __uint_as_float(u << 16); }
__device__ __forceinline__ float bfhi(unsigned u){ return __uint_as_float(u & 0xFFFF0000u); }
__device__ __forceinline__ unsigned bnrelu2(unsigned u, float s0, float h0, float s1, float h1){
  float v0 = fmaxf(fmaf(bflo(u), s0, h0), 0.f);
  float v1 = fmaxf(fmaf(bfhi(u), s1, h1), 0.f);
  return (unsigned)f2bf(v0) | ((unsigned)f2bf(v1) << 16);
}
__device__ __forceinline__ unsigned relupk(unsigned u){ // zero negative bf16 halves
  unsigned m = ((u >> 15) & 0x10001u) * 0xFFFFu;
  return u & ~m;
}

// ---------------- bucket-scatter into fixed slabs (+ weight pack on blocks 0..19) ----------------
__global__ __launch_bounds__(256) void k_bucket(const int* __restrict__ rows, const int* __restrict__ cols,
                                                int* __restrict__ pcur, uint2* __restrict__ ebuf,
                                                const float* __restrict__ W1, const float* __restrict__ W2,
                                                const float* __restrict__ W3,
                                                unsigned short* __restrict__ Wp1, unsigned short* __restrict__ Wp2,
                                                unsigned short* __restrict__ Wp3){
  __shared__ int bc[NBUCK];
  __shared__ int boff[NBUCK];
  __shared__ int ccur[NBUCK];
  __shared__ int gbase[NBUCK];
  __shared__ uint2 stage[CH];
  const int t = threadIdx.x;
  const int base = blockIdx.x * CH;
  const int nval = min(CH, EE - base);

  for (int i = t; i < NBUCK; i += 256) bc[i] = 0;
  __syncthreads();

  int er[16], ec[16];
  #pragma unroll
  for (int j = 0; j < 16; ++j){
    int i = j*256 + t;
    if (i < nval){
      er[j] = rows[base+i]; ec[j] = cols[base+i];
      atomicAdd(&bc[er[j] >> 9], 1);
    } else er[j] = -1;
  }
  __syncthreads();

  if (t < 64){ // wave-0 scan of bc -> boff
    int lane = t, run = 0;
    for (int c = 0; c < NBUCK; c += 64){
      int i = c + lane;
      int v = (i < NBUCK) ? bc[i] : 0;
      int s = v;
      #pragma unroll
      for (int d = 1; d < 64; d <<= 1){ int u = __shfl_up(s, d); if (lane >= d) s += u; }
      if (i < NBUCK) boff[i] = run + s - v;
      run += __shfl(s, 63);
    }
  }
  __syncthreads();
  if (t < NBUCK){
    gbase[t] = bc[t] ? (t*SLAB + atomicAdd(&pcur[t], bc[t])) : 0;
    ccur[t]  = boff[t];
  }
  __syncthreads();
  #pragma unroll
  for (int j = 0; j < 16; ++j){
    if (er[j] >= 0){
      int b = er[j] >> 9;
      int p = atomicAdd(&ccur[b], 1);
      stage[p] = make_uint2((unsigned)er[j], (unsigned)ec[j]);
    }
  }
  __syncthreads();
  for (int i = t; i < nval; i += 256){
    uint2 e = stage[i];
    int b = (int)(e.x >> 9);
    ebuf[gbase[b] + (i - boff[b])] = e;
  }

  // weight pack on first 20 blocks
  int b = blockIdx.x;
  if (b < 20){
    const float* W; unsigned short* Wp; int outc, i0;
    if (b < 8)      { W=W1; Wp=Wp1; outc=128; i0 = b*256; }
    else if (b < 16){ W=W2; Wp=Wp2; outc=128; i0 = (b-8)*256; }
    else            { W=W3; Wp=Wp3; outc=64;  i0 = (b-16)*256; }
    int i = i0 + t;
    if (i < 16*outc){
      int kb = i / outc, n = i - kb*outc;
      unsigned pk[4];
      #pragma unroll
      for (int jj = 0; jj < 4; ++jj){
        unsigned lo = f2bf(W[(size_t)(kb*8 + 2*jj)*outc + n]);
        unsigned hi = f2bf(W[(size_t)(kb*8 + 2*jj+1)*outc + n]);
        pk[jj] = lo | (hi << 16);
      }
      *reinterpret_cast<uint4*>(Wp + (size_t)i*8) = make_uint4(pk[0],pk[1],pk[2],pk[3]);
    }
  }
}

// ---------------- per-bucket CSR finalize (slab layout) ----------------
__global__ __launch_bounds__(256) void k_build(const uint2* __restrict__ ebuf,
                                               const int* __restrict__ pcur,
                                               int* __restrict__ row_start, int* __restrict__ cnt,
                                               float* __restrict__ dinv, int* __restrict__ csr_col){
  __shared__ int hist[512];
  __shared__ int cur[512];
  __shared__ int sCbase;
  const int b = blockIdx.x;
  const int row0 = b << 9;
  const int nrow = min(512, NN - row0);
  const int ebase = b * SLAB;
  const int ne = pcur[b];
  const int t = threadIdx.x;

  if (t < 64){ // csr base = sum pcur[0..b)
    int acc = 0;
    for (int i = t; i < b; i += 64) acc += pcur[i];
    #pragma unroll
    for (int d = 32; d; d >>= 1) acc += __shfl_xor(acc, d);
    if (t == 0) sCbase = acc;
  }
  for (int i = t; i < nrow; i += 256) hist[i] = 0;
  __syncthreads();
  for (int i = t; i < ne; i += 256)
    atomicAdd(&hist[(int)ebuf[ebase+i].x - row0], 1);
  __syncthreads();

  if (t < 64){
    int lane = t, run = 0;
    for (int c = 0; c < nrow; c += 64){
      int i = c + lane;
      int v = (i < nrow) ? hist[i] : 0;
      int s = v;
      #pragma unroll
      for (int d = 1; d < 64; d <<= 1){ int u = __shfl_up(s, d); if (lane >= d) s += u; }
      if (i < nrow) cur[i] = run + s - v;
      run += __shfl(s, 63);
    }
  }
  __syncthreads();
  const int cbase = sCbase;
  for (int i = t; i < nrow; i += 256){
    int h = hist[i];
    int r = row0 + i;
    cnt[r] = h;
    dinv[r] = rsqrtf((float)(h+1));
    row_start[r] = cbase + cur[i];
    cur[i] += cbase;
  }
  __syncthreads();
  for (int i = t; i < ne; i += 256){
    uint2 e = ebuf[ebase+i];
    int p = atomicAdd(&cur[(int)e.x - row0], 1);
    csr_col[p] = (int)e.y;
  }
}

// ---------------- sliced aggregation: slice = blockIdx&7 -> XCD-local L2 gather ----------------
// hs layout: [8][NN][8 uints] (32 B = 16 bf16 features per node per slice)
__global__ __launch_bounds__(256) void k_aggs(const unsigned* __restrict__ hs,
                                              const int* __restrict__ row_start,
                                              const int* __restrict__ cnt,
                                              const int* __restrict__ col,
                                              const float* __restrict__ dinv,
                                              const float* __restrict__ bias,
                                              unsigned* __restrict__ outs){
  const int bid = blockIdx.x;
  const int s   = bid & 7;                 // XCD slice
  const int rb  = bid >> 3;                // 32-row block
  const int wv  = __builtin_amdgcn_readfirstlane((int)(threadIdx.x >> 6));
  const int lane = threadIdx.x & 63;
  const int g   = lane >> 3;               // edge slot 0..7
  const int j8  = lane & 7;                // 4B chunk within 32B slice row
  const unsigned* hp = hs + (size_t)s*NN*8 + j8;
  const float2 bb = *reinterpret_cast<const float2*>(bias + 16*s + 2*j8);

  for (int r8 = 0; r8 < 8; ++r8){
    int wid = rb*32 + wv*8 + r8;           // NN = 3125*32, always valid
    int p = row_start[wid];                // uniform -> scalar
    int n1 = cnt[wid] + 1;                 // items: self + edges
    float dr = dinv[wid];
    float a0 = 0.f, a1 = 0.f;
    for (int base0 = 0; base0 < n1; base0 += 8){
      int idx = base0 + g;
      int cc = wid;
      if (idx > 0 && idx < n1) cc = col[p + idx - 1];
      unsigned u = 0;
      if (idx < n1) u = hp[(size_t)cc*8];
      a0 += bflo(u); a1 += bfhi(u);
    }
    a0 += __shfl_xor(a0, 8);  a1 += __shfl_xor(a1, 8);
    a0 += __shfl_xor(a0, 16); a1 += __shfl_xor(a1, 16);
    a0 += __shfl_xor(a0, 32); a1 += __shfl_xor(a1, 32);
    float o0 = a0*dr + bb.x, o1 = a1*dr + bb.y;
    unsigned pk = (unsigned)f2bf(o0) | ((unsigned)f2bf(o1) << 16);
    if (lane < 8)
      outs[((size_t)s*NN + wid)*8 + j8] = pk;
  }
}

// ---------------- MFMA GEMM: C[N x OUTC] = xform(A[N x 128]) * W ----------------
// XFORM: 0 none, 1 BN(scale,shift)+relu, 2 relu
// ASLICED: A is sliced bf16 [8][NN][32B]; else fp32 row-major
// OUTSLICED: write sliced bf16 * dinv; else fp32 row-major + bias
template<int OUTC, int XFORM, bool OUTSLICED, bool ASLICED>
__global__ __launch_bounds__(256) void k_mgemm(const void* __restrict__ Av,
                                               const unsigned short* __restrict__ Wp,
                                               const float* __restrict__ scale,
                                               const float* __restrict__ shiftv,
                                               const float* __restrict__ bias,
                                               const float* __restrict__ dinv,
                                               void* __restrict__ Cv){
  __shared__ char AsB[32768];   // 128 rows x 256 B bf16, XOR-swizzled
  const int t = threadIdx.x;
  const int row0 = blockIdx.x * 128;

  if constexpr (ASLICED){
    const unsigned* A = (const unsigned*)Av;
    const int sg = t >> 5;               // slice group 0..7
    const int i  = t & 31;
    const int q  = i & 1;                // which 16B half of 32B slice row
    float4 sc01, sc23, sh01, sh23;
    if (XFORM == 1){
      int fb = 16*sg + 8*q;
      sc01 = *reinterpret_cast<const float4*>(scale + fb);
      sc23 = *reinterpret_cast<const float4*>(scale + fb + 4);
      sh01 = *reinterpret_cast<const float4*>(shiftv + fb);
      sh23 = *reinterpret_cast<const float4*>(shiftv + fb + 4);
    }
    const uint4* src = reinterpret_cast<const uint4*>(A + ((size_t)sg*NN + row0)*8);
    #pragma unroll
    for (int k = 0; k < 8; ++k){
      int u = i + 32*k;                  // 0..255
      int r = u >> 1;                    // row 0..127
      uint4 v = src[u];                  // tail rows >= NN: garbage, discarded in epilogue
      if (XFORM == 1){
        v.x = bnrelu2(v.x, sc01.x, sh01.x, sc01.y, sh01.y);
        v.y = bnrelu2(v.y, sc01.z, sh01.z, sc01.w, sh01.w);
        v.z = bnrelu2(v.z, sc23.x, sh23.x, sc23.y, sh23.y);
        v.w = bnrelu2(v.w, sc23.z, sh23.z, sc23.w, sh23.w);
      } else if (XFORM == 2){
        v.x = relupk(v.x); v.y = relupk(v.y); v.z = relupk(v.z); v.w = relupk(v.w);
      }
      int boff = (32*sg + 16*q) ^ ((r & 7) << 4);
      *reinterpret_cast<uint4*>(AsB + r*256 + boff) = v;
    }
  } else { // fp32 row-major A -> bf16
    const float* A = (const float*)Av;
    #pragma unroll
    for (int gg = 0; gg < 16; ++gg){
      int f = gg*256 + t;
      int r = f >> 5;
      int c4 = f & 31;
      int row = row0 + r;
      int rc = row < NN ? row : NN-1;
      float4 v = *reinterpret_cast<const float4*>(A + (size_t)rc*HN + c4*4);
      unsigned p0 = (unsigned)f2bf(v.x) | ((unsigned)f2bf(v.y) << 16);
      unsigned p1 = (unsigned)f2bf(v.z) | ((unsigned)f2bf(v.w) << 16);
      int boff = (c4*8) ^ ((r & 7) << 4);
      *reinterpret_cast<uint2*>(AsB + r*256 + boff) = make_uint2(p0, p1);
    }
  }
  __syncthreads();

  const int wv = t >> 6;
  const int l  = t & 63;
  const int lm = l & 15;
  const int lk = l >> 4;
  constexpr int NF = OUTC/16;

  f32x4 acc[2][NF];
  #pragma unroll
  for (int mi=0;mi<2;++mi)
    #pragma unroll
    for (int ni=0;ni<NF;++ni) acc[mi][ni] = (f32x4){0.f,0.f,0.f,0.f};

  const bf16x8* WpV = reinterpret_cast<const bf16x8*>(Wp);

  #pragma unroll
  for (int ks = 0; ks < 4; ++ks){
    bf16x8 af[2];
    #pragma unroll
    for (int mi=0;mi<2;++mi){
      int R = wv*32 + mi*16 + lm;
      int boff = (ks*64 + lk*16) ^ ((R & 7) << 4);
      af[mi] = *reinterpret_cast<const bf16x8*>(AsB + R*256 + boff);
    }
    int kb = ks*4 + lk;
    #pragma unroll
    for (int ni=0;ni<NF;++ni){
      int n = ni*16 + lm;
      bf16x8 bfr = WpV[kb*OUTC + n];
      acc[0][ni] = __builtin_amdgcn_mfma_f32_16x16x32_bf16(af[0], bfr, acc[0][ni], 0,0,0);
      acc[1][ni] = __builtin_amdgcn_mfma_f32_16x16x32_bf16(af[1], bfr, acc[1][ni], 0,0,0);
    }
  }

  // epilogue. D frag (mi,ni): row = wv*32+mi*16+lk*4+j, col = ni*16+lm
  #pragma unroll
  for (int mi=0;mi<2;++mi){
    #pragma unroll
    for (int j=0;j<4;++j){
      int grow = row0 + wv*32 + mi*16 + lk*4 + j;
      if (grow >= NN) continue;                    // uniform across shfl pair (lm-independent)
      if constexpr (OUTSLICED){
        float dr = dinv[grow];
        #pragma unroll
        for (int ni=0;ni<NF;++ni){
          unsigned u16 = (unsigned)f2bf(acc[mi][ni][j] * dr);
          unsigned partner = (unsigned)__shfl_xor((int)u16, 1);
          if (!(lm & 1)){
            unsigned pk = u16 | (partner << 16);   // features (16ni+lm, +1)
            *reinterpret_cast<unsigned*>((char*)Cv + ((size_t)ni*NN + grow)*32 + lm*2) = pk;
          }
        }
      } else {
        float* po = (float*)Cv + (size_t)grow*OUTC;
        #pragma unroll
        for (int ni=0;ni<NF;++ni)
          po[ni*16 + lm] = acc[mi][ni][j] + bias[ni*16 + lm];
      }
    }
  }
}

// ---------------- BN stats over sliced bf16 rows (two-stage, separate dispatches) ----------------
__global__ __launch_bounds__(256) void k_stats(const unsigned* __restrict__ a,
                                               float* __restrict__ ps, float* __restrict__ pq){
  __shared__ float l0[256], l1[256], m0[256], m1[256];
  const int lane = threadIdx.x & 63;
  const int grp  = threadIdx.x >> 6;
  const int s  = lane >> 3;
  const int j8 = lane & 7;
  const unsigned* ap = a + (size_t)s*NN*8 + j8;
  float s0=0.f,s1=0.f,q0=0.f,q1=0.f;
  for (int r = blockIdx.x*4 + grp; r < NN; r += SB*4){
    unsigned u = ap[(size_t)r*8];
    float v0 = bflo(u), v1 = bfhi(u);
    s0 += v0; s1 += v1; q0 = fmaf(v0,v0,q0); q1 = fmaf(v1,v1,q1);
  }
  l0[threadIdx.x]=s0; l1[threadIdx.x]=s1; m0[threadIdx.x]=q0; m1[threadIdx.x]=q1;
  __syncthreads();
  if (grp==0){
    #pragma unroll
    for (int g2=1;g2<4;++g2){ s0+=l0[g2*64+lane]; s1+=l1[g2*64+lane]; q0+=m0[g2*64+lane]; q1+=m1[g2*64+lane]; }
    int f0 = 16*s + 2*j8;
    ps[blockIdx.x*128 + f0]   = s0; ps[blockIdx.x*128 + f0+1] = s1;
    pq[blockIdx.x*128 + f0]   = q0; pq[blockIdx.x*128 + f0+1] = q1;
  }
}

__global__ __launch_bounds__(128) void k_bnfinal(const float* __restrict__ ps, const float* __restrict__ pq,
                                                 const float* __restrict__ gamma, const float* __restrict__ beta,
                                                 float* __restrict__ scale, float* __restrict__ shiftv){
  int c = threadIdx.x;
  float s=0.f, q=0.f;
  for (int b=0;b<SB;b++){ s += ps[b*128+c]; q += pq[b*128+c]; }
  float mean = s * (1.0f/NN);
  float var  = q * (1.0f/NN) - mean*mean;
  float inv  = rsqrtf(var + 1e-5f);
  float sc = gamma[c]*inv;
  scale[c]  = sc;
  shiftv[c] = beta[c] - mean*sc;
}

// ---------------- launch ----------------
extern "C" void kernel_launch(void* const* d_in, const int* in_sizes, int n_in,
                              void* d_out, int out_size, void* d_ws, size_t ws_size,
                              hipStream_t stream) {
  const float* x      = (const float*)d_in[0];
  const int*   ei     = (const int*)d_in[1];
  const int*   rows   = ei;
  const int*   cols   = ei + EE;
  const float* W1     = (const float*)d_in[2];
  const float* b1     = (const float*)d_in[3];
  const float* gamma1 = (const float*)d_in[4];
  const float* beta1  = (const float*)d_in[5];
  const float* W2     = (const float*)d_in[6];
  const float* b2     = (const float*)d_in[7];
  const float* W3     = (const float*)d_in[8];
  const float* b3     = (const float*)d_in[9];
  float* out = (float*)d_out;

  char* w = (char*)d_ws;
  float* buf0      = (float*)w; w += (size_t)NN*HN*4;   // ebuf slabs (25.7MB) then hbf sliced (25.6MB)
  float* buf1      = (float*)w; w += (size_t)NN*HN*4;   // abf sliced
  int*   csr_col   = (int*)w;   w += (size_t)EE*4;
  int*   row_start = (int*)w;   w += (size_t)NN*4;
  int*   cnt       = (int*)w;   w += (size_t)NN*4;
  float* dinv      = (float*)w; w += (size_t)NN*4;
  float* ps        = (float*)w; w += (size_t)SB*128*4;
  float* pq        = (float*)w; w += (size_t)SB*128*4;
  float* scale     = (float*)w; w += 1024;
  float* shiftv    = (float*)w; w += 1024;
  int*   scr0      = (int*)w;   w += 4096;   // pcur[256]
  unsigned short* Wp1 = (unsigned short*)w; w += 128*128*2;
  unsigned short* Wp2 = (unsigned short*)w; w += 128*128*2;
  unsigned short* Wp3 = (unsigned short*)w; w += 128*64*2;
  int* pcur = scr0;
  uint2*    ebuf  = (uint2*)buf0;      // dead before mgemm1 writes hbf
  unsigned* hbf   = (unsigned*)buf0;   // sliced h [8][NN][8 uints]
  unsigned* abf   = (unsigned*)buf1;   // sliced agg output

  (void)hipMemsetAsync(scr0, 0, 4096, stream);

  const int CB = (EE + CH - 1)/CH, GB = (NN+127)/128, AB = (NN/32)*8;

  k_bucket<<<CB, 256, 0, stream>>>(rows, cols, pcur, ebuf, W1, W2, W3, Wp1, Wp2, Wp3);
  k_build <<<NBUCK, 256, 0, stream>>>(ebuf, pcur, row_start, cnt, dinv, csr_col);

  // layer 1: h1' = bf16((x@W1)*dinv) sliced; agg -> abf sliced (+b1); BN stats (two dispatches)
  k_mgemm<128,0,true,false><<<GB, 256, 0, stream>>>(x, Wp1, nullptr, nullptr, nullptr, dinv, hbf);
  k_aggs<<<AB, 256, 0, stream>>>(hbf, row_start, cnt, csr_col, dinv, b1, abf);
  k_stats<<<SB, 256, 0, stream>>>(abf, ps, pq);
  k_bnfinal<<<1, 128, 0, stream>>>(ps, pq, gamma1, beta1, scale, shiftv);

  // layer 2: BN+relu fused into sliced staging; h2' sliced
  k_mgemm<128,1,true,true><<<GB, 256, 0, stream>>>(abf, Wp2, scale, shiftv, nullptr, dinv, hbf);
  k_aggs<<<AB, 256, 0, stream>>>(hbf, row_start, cnt, csr_col, dinv, b2, abf);

  // layer 3: relu fused into sliced staging; fp32 out + b3
  k_mgemm<64,2,false,true><<<GB, 256, 0, stream>>>(abf, Wp3, nullptr, nullptr, b3, nullptr, out);
}

// Round 11
// 445.429 us; speedup vs baseline: 1.0770x; 1.0770x over previous
//
#include <hip/hip_runtime.h>

#define NN 100000
#define EE 1600000
#define HN 128
#define OO 64
#define SB 256     // stats blocks
#define NBUCK 196  // ceil(NN/512), bucket = row >> 9
#define CH 4096    // edges per bucketing chunk
#define SLAB 16384 // fixed slab per bucket (mean 8192, +90 sigma safe)

typedef __attribute__((ext_vector_type(8))) short bf16x8;
typedef __attribute__((ext_vector_type(4))) float f32x4;

__device__ __forceinline__ unsigned short f2bf(float f){ // RNE bf16
  unsigned u = __float_as_uint(f);
  return (unsigned short)((u + 0x7FFFu + ((u >> 16) & 1u)) >> 16);
}
__device__ __forceinline__ float bflo(unsigned u){ return __uint_as_float(u << 16); }
__device__ __forceinline__ float bfhi(unsigned u){ return __uint_as_float(u & 0xFFFF0000u); }
__device__ __forceinline__ unsigned bnrelu2(unsigned u, float s0, float h0, float s1, float h1){
  float v0 = fmaxf(fmaf(bflo(u), s0, h0), 0.f);
  float v1 = fmaxf(fmaf(bfhi(u), s1, h1), 0.f);
  return (unsigned)f2bf(v0) | ((unsigned)f2bf(v1) << 16);
}
__device__ __forceinline__ unsigned relupk(unsigned u){ // zero negative bf16 halves
  unsigned m = ((u >> 15) & 0x10001u) * 0xFFFFu;
  return u & ~m;
}

// ---------------- bucket-scatter into fixed slabs (+ weight pack on blocks 0..19) ----------------
__global__ __launch_bounds__(256) void k_bucket(const int* __restrict__ rows, const int* __restrict__ cols,
                                                int* __restrict__ pcur, uint2* __restrict__ ebuf,
                                                const float* __restrict__ W1, const float* __restrict__ W2,
                                                const float* __restrict__ W3,
                                                unsigned short* __restrict__ Wp1, unsigned short* __restrict__ Wp2,
                                                unsigned short* __restrict__ Wp3){
  __shared__ int bc[NBUCK];
  __shared__ int boff[NBUCK];
  __shared__ int ccur[NBUCK];
  __shared__ int gbase[NBUCK];
  __shared__ uint2 stage[CH];
  const int t = threadIdx.x;
  const int base = blockIdx.x * CH;
  const int nval = min(CH, EE - base);

  for (int i = t; i < NBUCK; i += 256) bc[i] = 0;
  __syncthreads();

  int er[16], ec[16];
  #pragma unroll
  for (int j = 0; j < 16; ++j){
    int i = j*256 + t;
    if (i < nval){
      er[j] = rows[base+i]; ec[j] = cols[base+i];
      atomicAdd(&bc[er[j] >> 9], 1);
    } else er[j] = -1;
  }
  __syncthreads();

  if (t < 64){ // wave-0 scan of bc -> boff
    int lane = t, run = 0;
    for (int c = 0; c < NBUCK; c += 64){
      int i = c + lane;
      int v = (i < NBUCK) ? bc[i] : 0;
      int s = v;
      #pragma unroll
      for (int d = 1; d < 64; d <<= 1){ int u = __shfl_up(s, d); if (lane >= d) s += u; }
      if (i < NBUCK) boff[i] = run + s - v;
      run += __shfl(s, 63);
    }
  }
  __syncthreads();
  if (t < NBUCK){
    gbase[t] = bc[t] ? (t*SLAB + atomicAdd(&pcur[t], bc[t])) : 0;
    ccur[t]  = boff[t];
  }
  __syncthreads();
  #pragma unroll
  for (int j = 0; j < 16; ++j){
    if (er[j] >= 0){
      int b = er[j] >> 9;
      int p = atomicAdd(&ccur[b], 1);
      stage[p] = make_uint2((unsigned)er[j], (unsigned)ec[j]);
    }
  }
  __syncthreads();
  for (int i = t; i < nval; i += 256){
    uint2 e = stage[i];
    int b = (int)(e.x >> 9);
    ebuf[gbase[b] + (i - boff[b])] = e;
  }

  // weight pack on first 20 blocks
  int b = blockIdx.x;
  if (b < 20){
    const float* W; unsigned short* Wp; int outc, i0;
    if (b < 8)      { W=W1; Wp=Wp1; outc=128; i0 = b*256; }
    else if (b < 16){ W=W2; Wp=Wp2; outc=128; i0 = (b-8)*256; }
    else            { W=W3; Wp=Wp3; outc=64;  i0 = (b-16)*256; }
    int i = i0 + t;
    if (i < 16*outc){
      int kb = i / outc, n = i - kb*outc;
      unsigned pk[4];
      #pragma unroll
      for (int jj = 0; jj < 4; ++jj){
        unsigned lo = f2bf(W[(size_t)(kb*8 + 2*jj)*outc + n]);
        unsigned hi = f2bf(W[(size_t)(kb*8 + 2*jj+1)*outc + n]);
        pk[jj] = lo | (hi << 16);
      }
      *reinterpret_cast<uint4*>(Wp + (size_t)i*8) = make_uint4(pk[0],pk[1],pk[2],pk[3]);
    }
  }
}

// ---------------- per-bucket CSR finalize (slab layout) ----------------
__global__ __launch_bounds__(256) void k_build(const uint2* __restrict__ ebuf,
                                               const int* __restrict__ pcur,
                                               int* __restrict__ row_start, int* __restrict__ cnt,
                                               float* __restrict__ dinv, int* __restrict__ csr_col){
  __shared__ int hist[512];
  __shared__ int cur[512];
  __shared__ int sCbase;
  const int b = blockIdx.x;
  const int row0 = b << 9;
  const int nrow = min(512, NN - row0);
  const int ebase = b * SLAB;
  const int ne = pcur[b];
  const int t = threadIdx.x;

  if (t < 64){ // csr base = sum pcur[0..b)
    int acc = 0;
    for (int i = t; i < b; i += 64) acc += pcur[i];
    #pragma unroll
    for (int d = 32; d; d >>= 1) acc += __shfl_xor(acc, d);
    if (t == 0) sCbase = acc;
  }
  for (int i = t; i < nrow; i += 256) hist[i] = 0;
  __syncthreads();
  for (int i = t; i < ne; i += 256)
    atomicAdd(&hist[(int)ebuf[ebase+i].x - row0], 1);
  __syncthreads();

  if (t < 64){
    int lane = t, run = 0;
    for (int c = 0; c < nrow; c += 64){
      int i = c + lane;
      int v = (i < nrow) ? hist[i] : 0;
      int s = v;
      #pragma unroll
      for (int d = 1; d < 64; d <<= 1){ int u = __shfl_up(s, d); if (lane >= d) s += u; }
      if (i < nrow) cur[i] = run + s - v;
      run += __shfl(s, 63);
    }
  }
  __syncthreads();
  const int cbase = sCbase;
  for (int i = t; i < nrow; i += 256){
    int h = hist[i];
    int r = row0 + i;
    cnt[r] = h;
    dinv[r] = rsqrtf((float)(h+1));
    row_start[r] = cbase + cur[i];
    cur[i] += cbase;
  }
  __syncthreads();
  for (int i = t; i < ne; i += 256){
    uint2 e = ebuf[ebase+i];
    int p = atomicAdd(&cur[(int)e.x - row0], 1);
    csr_col[p] = (int)e.y;
  }
}

// ---------------- sliced aggregation, MLP-restored: one row-task per wave ----------------
// hs layout: [8][NN][8 uints] (32 B = 16 bf16 features per node per slice)
// grid = (NN/4) row-blocks x 8 slices; block = 4 waves, wave = one row of one slice.
// lane = (g = edge slot 0..7, j8 = 4B chunk). Batched col loads + independent gathers.
__global__ __launch_bounds__(256) void k_aggs(const unsigned* __restrict__ hs,
                                              const int* __restrict__ row_start,
                                              const int* __restrict__ cnt,
                                              const int* __restrict__ col,
                                              const float* __restrict__ dinv,
                                              const float* __restrict__ bias,
                                              unsigned* __restrict__ outs){
  const int bid = blockIdx.x;
  const int s   = bid & 7;                 // XCD slice
  const int rb  = bid >> 3;                // row-block (NN/4)
  const int wv  = __builtin_amdgcn_readfirstlane((int)(threadIdx.x >> 6));
  const int lane = threadIdx.x & 63;
  const int g   = lane >> 3;
  const int j8  = lane & 7;
  const unsigned* hp = hs + (size_t)s*NN*8 + j8;
  const float2 bb = *reinterpret_cast<const float2*>(bias + 16*s + 2*j8);

  const int wid = rb*4 + wv;               // NN % 4 == 0, always valid; uniform per wave
  const int p  = row_start[wid];           // scalar loads
  const int n1 = cnt[wid] + 1;             // slots: 0 = self, 1.. = edges
  const float dr = dinv[wid];

  // batched col-index loads (slots 0..31), all independent
  int cc[4];
  #pragma unroll
  for (int i = 0; i < 4; ++i){
    int idx = i*8 + g;
    int c = wid;
    if (idx > 0 && idx < n1) c = col[p + idx - 1];
    cc[i] = c;                             // always a valid row index
  }
  // independent gathers; invalid slots zeroed after the load
  float a0 = 0.f, a1 = 0.f;
  #pragma unroll
  for (int i = 0; i < 4; ++i){
    unsigned u = hp[(size_t)cc[i]*8];
    if (i*8 + g >= n1) u = 0;
    a0 += bflo(u); a1 += bfhi(u);
  }
  // rare tail (deg > 31)
  for (int base0 = 32; base0 < n1; base0 += 8){
    int idx = base0 + g;
    int c = wid;
    if (idx < n1) c = col[p + idx - 1];
    unsigned u = hp[(size_t)c*8];
    if (idx >= n1) u = 0;
    a0 += bflo(u); a1 += bfhi(u);
  }

  a0 += __shfl_xor(a0, 8);  a1 += __shfl_xor(a1, 8);
  a0 += __shfl_xor(a0, 16); a1 += __shfl_xor(a1, 16);
  a0 += __shfl_xor(a0, 32); a1 += __shfl_xor(a1, 32);

  if (lane < 8){
    float o0 = a0*dr + bb.x, o1 = a1*dr + bb.y;
    unsigned pk = (unsigned)f2bf(o0) | ((unsigned)f2bf(o1) << 16);
    outs[((size_t)s*NN + wid)*8 + j8] = pk;
  }
}

// ---------------- MFMA GEMM: C[N x OUTC] = xform(A[N x 128]) * W ----------------
// XFORM: 0 none, 1 BN(scale,shift)+relu, 2 relu
// ASLICED: A is sliced bf16 [8][NN][32B]; else fp32 row-major
// OUTSLICED: write sliced bf16 * dinv; else fp32 row-major + bias
template<int OUTC, int XFORM, bool OUTSLICED, bool ASLICED>
__global__ __launch_bounds__(256) void k_mgemm(const void* __restrict__ Av,
                                               const unsigned short* __restrict__ Wp,
                                               const float* __restrict__ scale,
                                               const float* __restrict__ shiftv,
                                               const float* __restrict__ bias,
                                               const float* __restrict__ dinv,
                                               void* __restrict__ Cv){
  __shared__ char AsB[32768];   // 128 rows x 256 B bf16, XOR-swizzled
  const int t = threadIdx.x;
  const int row0 = blockIdx.x * 128;

  if constexpr (ASLICED){
    const unsigned* A = (const unsigned*)Av;
    const int sg = t >> 5;               // slice group 0..7
    const int i  = t & 31;
    const int q  = i & 1;                // which 16B half of 32B slice row
    float4 sc01, sc23, sh01, sh23;
    if (XFORM == 1){
      int fb = 16*sg + 8*q;
      sc01 = *reinterpret_cast<const float4*>(scale + fb);
      sc23 = *reinterpret_cast<const float4*>(scale + fb + 4);
      sh01 = *reinterpret_cast<const float4*>(shiftv + fb);
      sh23 = *reinterpret_cast<const float4*>(shiftv + fb + 4);
    }
    const uint4* src = reinterpret_cast<const uint4*>(A + ((size_t)sg*NN + row0)*8);
    #pragma unroll
    for (int k = 0; k < 8; ++k){
      int u = i + 32*k;                  // 0..255
      int r = u >> 1;                    // row 0..127
      uint4 v = src[u];                  // tail rows >= NN: garbage, discarded in epilogue
      if (XFORM == 1){
        v.x = bnrelu2(v.x, sc01.x, sh01.x, sc01.y, sh01.y);
        v.y = bnrelu2(v.y, sc01.z, sh01.z, sc01.w, sh01.w);
        v.z = bnrelu2(v.z, sc23.x, sh23.x, sc23.y, sh23.y);
        v.w = bnrelu2(v.w, sc23.z, sh23.z, sc23.w, sh23.w);
      } else if (XFORM == 2){
        v.x = relupk(v.x); v.y = relupk(v.y); v.z = relupk(v.z); v.w = relupk(v.w);
      }
      int boff = (32*sg + 16*q) ^ ((r & 7) << 4);
      *reinterpret_cast<uint4*>(AsB + r*256 + boff) = v;
    }
  } else { // fp32 row-major A -> bf16
    const float* A = (const float*)Av;
    #pragma unroll
    for (int gg = 0; gg < 16; ++gg){
      int f = gg*256 + t;
      int r = f >> 5;
      int c4 = f & 31;
      int row = row0 + r;
      int rc = row < NN ? row : NN-1;
      float4 v = *reinterpret_cast<const float4*>(A + (size_t)rc*HN + c4*4);
      unsigned p0 = (unsigned)f2bf(v.x) | ((unsigned)f2bf(v.y) << 16);
      unsigned p1 = (unsigned)f2bf(v.z) | ((unsigned)f2bf(v.w) << 16);
      int boff = (c4*8) ^ ((r & 7) << 4);
      *reinterpret_cast<uint2*>(AsB + r*256 + boff) = make_uint2(p0, p1);
    }
  }
  __syncthreads();

  const int wv = t >> 6;
  const int l  = t & 63;
  const int lm = l & 15;
  const int lk = l >> 4;
  constexpr int NF = OUTC/16;

  f32x4 acc[2][NF];
  #pragma unroll
  for (int mi=0;mi<2;++mi)
    #pragma unroll
    for (int ni=0;ni<NF;++ni) acc[mi][ni] = (f32x4){0.f,0.f,0.f,0.f};

  const bf16x8* WpV = reinterpret_cast<const bf16x8*>(Wp);

  #pragma unroll
  for (int ks = 0; ks < 4; ++ks){
    bf16x8 af[2];
    #pragma unroll
    for (int mi=0;mi<2;++mi){
      int R = wv*32 + mi*16 + lm;
      int boff = (ks*64 + lk*16) ^ ((R & 7) << 4);
      af[mi] = *reinterpret_cast<const bf16x8*>(AsB + R*256 + boff);
    }
    int kb = ks*4 + lk;
    #pragma unroll
    for (int ni=0;ni<NF;++ni){
      int n = ni*16 + lm;
      bf16x8 bfr = WpV[kb*OUTC + n];
      acc[0][ni] = __builtin_amdgcn_mfma_f32_16x16x32_bf16(af[0], bfr, acc[0][ni], 0,0,0);
      acc[1][ni] = __builtin_amdgcn_mfma_f32_16x16x32_bf16(af[1], bfr, acc[1][ni], 0,0,0);
    }
  }

  // epilogue. D frag (mi,ni): row = wv*32+mi*16+lk*4+j, col = ni*16+lm
  #pragma unroll
  for (int mi=0;mi<2;++mi){
    #pragma unroll
    for (int j=0;j<4;++j){
      int grow = row0 + wv*32 + mi*16 + lk*4 + j;
      if (grow >= NN) continue;                    // uniform across shfl pair (lm-independent)
      if constexpr (OUTSLICED){
        float dr = dinv[grow];
        #pragma unroll
        for (int ni=0;ni<NF;++ni){
          unsigned u16 = (unsigned)f2bf(acc[mi][ni][j] * dr);
          unsigned partner = (unsigned)__shfl_xor((int)u16, 1);
          if (!(lm & 1)){
            unsigned pk = u16 | (partner << 16);   // features (16ni+lm, +1)
            *reinterpret_cast<unsigned*>((char*)Cv + ((size_t)ni*NN + grow)*32 + lm*2) = pk;
          }
        }
      } else {
        float* po = (float*)Cv + (size_t)grow*OUTC;
        #pragma unroll
        for (int ni=0;ni<NF;++ni)
          po[ni*16 + lm] = acc[mi][ni][j] + bias[ni*16 + lm];
      }
    }
  }
}

// ---------------- BN stats over sliced bf16 rows (two-stage, separate dispatches) ----------------
__global__ __launch_bounds__(256) void k_stats(const unsigned* __restrict__ a,
                                               float* __restrict__ ps, float* __restrict__ pq){
  __shared__ float l0[256], l1[256], m0[256], m1[256];
  const int lane = threadIdx.x & 63;
  const int grp  = threadIdx.x >> 6;
  const int s  = lane >> 3;
  const int j8 = lane & 7;
  const unsigned* ap = a + (size_t)s*NN*8 + j8;
  float s0=0.f,s1=0.f,q0=0.f,q1=0.f;
  for (int r = blockIdx.x*4 + grp; r < NN; r += SB*4){
    unsigned u = ap[(size_t)r*8];
    float v0 = bflo(u), v1 = bfhi(u);
    s0 += v0; s1 += v1; q0 = fmaf(v0,v0,q0); q1 = fmaf(v1,v1,q1);
  }
  l0[threadIdx.x]=s0; l1[threadIdx.x]=s1; m0[threadIdx.x]=q0; m1[threadIdx.x]=q1;
  __syncthreads();
  if (grp==0){
    #pragma unroll
    for (int g2=1;g2<4;++g2){ s0+=l0[g2*64+lane]; s1+=l1[g2*64+lane]; q0+=m0[g2*64+lane]; q1+=m1[g2*64+lane]; }
    int f0 = 16*s + 2*j8;
    ps[blockIdx.x*128 + f0]   = s0; ps[blockIdx.x*128 + f0+1] = s1;
    pq[blockIdx.x*128 + f0]   = q0; pq[blockIdx.x*128 + f0+1] = q1;
  }
}

__global__ __launch_bounds__(128) void k_bnfinal(const float* __restrict__ ps, const float* __restrict__ pq,
                                                 const float* __restrict__ gamma, const float* __restrict__ beta,
                                                 float* __restrict__ scale, float* __restrict__ shiftv){
  int c = threadIdx.x;
  float s=0.f, q=0.f;
  for (int b=0;b<SB;b++){ s += ps[b*128+c]; q += pq[b*128+c]; }
  float mean = s * (1.0f/NN);
  float var  = q * (1.0f/NN) - mean*mean;
  float inv  = rsqrtf(var + 1e-5f);
  float sc = gamma[c]*inv;
  scale[c]  = sc;
  shiftv[c] = beta[c] - mean*sc;
}

// ---------------- launch ----------------
extern "C" void kernel_launch(void* const* d_in, const int* in_sizes, int n_in,
                              void* d_out, int out_size, void* d_ws, size_t ws_size,
                              hipStream_t stream) {
  const float* x      = (const float*)d_in[0];
  const int*   ei     = (const int*)d_in[1];
  const int*   rows   = ei;
  const int*   cols   = ei + EE;
  const float* W1     = (const float*)d_in[2];
  const float* b1     = (const float*)d_in[3];
  const float* gamma1 = (const float*)d_in[4];
  const float* beta1  = (const float*)d_in[5];
  const float* W2     = (const float*)d_in[6];
  const float* b2     = (const float*)d_in[7];
  const float* W3     = (const float*)d_in[8];
  const float* b3     = (const float*)d_in[9];
  float* out = (float*)d_out;

  char* w = (char*)d_ws;
  float* buf0      = (float*)w; w += (size_t)NN*HN*4;   // ebuf slabs (25.7MB) then hbf sliced (25.6MB)
  float* buf1      = (float*)w; w += (size_t)NN*HN*4;   // abf sliced
  int*   csr_col   = (int*)w;   w += (size_t)EE*4;
  int*   row_start = (int*)w;   w += (size_t)NN*4;
  int*   cnt       = (int*)w;   w += (size_t)NN*4;
  float* dinv      = (float*)w; w += (size_t)NN*4;
  float* ps        = (float*)w; w += (size_t)SB*128*4;
  float* pq        = (float*)w; w += (size_t)SB*128*4;
  float* scale     = (float*)w; w += 1024;
  float* shiftv    = (float*)w; w += 1024;
  int*   scr0      = (int*)w;   w += 4096;   // pcur[256]
  unsigned short* Wp1 = (unsigned short*)w; w += 128*128*2;
  unsigned short* Wp2 = (unsigned short*)w; w += 128*128*2;
  unsigned short* Wp3 = (unsigned short*)w; w += 128*64*2;
  int* pcur = scr0;
  uint2*    ebuf  = (uint2*)buf0;      // dead before mgemm1 writes hbf
  unsigned* hbf   = (unsigned*)buf0;   // sliced h [8][NN][8 uints]
  unsigned* abf   = (unsigned*)buf1;   // sliced agg output

  (void)hipMemsetAsync(scr0, 0, 4096, stream);

  const int CB = (EE + CH - 1)/CH, GB = (NN+127)/128, AB = (NN/4)*8;

  k_bucket<<<CB, 256, 0, stream>>>(rows, cols, pcur, ebuf, W1, W2, W3, Wp1, Wp2, Wp3);
  k_build <<<NBUCK, 256, 0, stream>>>(ebuf, pcur, row_start, cnt, dinv, csr_col);

  // layer 1: h1' = bf16((x@W1)*dinv) sliced; agg -> abf sliced (+b1); BN stats
  k_mgemm<128,0,true,false><<<GB, 256, 0, stream>>>(x, Wp1, nullptr, nullptr, nullptr, dinv, hbf);
  k_aggs<<<AB, 256, 0, stream>>>(hbf, row_start, cnt, csr_col, dinv, b1, abf);
  k_stats<<<SB, 256, 0, stream>>>(abf, ps, pq);
  k_bnfinal<<<1, 128, 0, stream>>>(ps, pq, gamma1, beta1, scale, shiftv);

  // layer 2: BN+relu fused into sliced staging; h2' sliced
  k_mgemm<128,1,true,true><<<GB, 256, 0, stream>>>(abf, Wp2, scale, shiftv, nullptr, dinv, hbf);
  k_aggs<<<AB, 256, 0, stream>>>(hbf, row_start, cnt, csr_col, dinv, b2, abf);

  // layer 3: relu fused into sliced staging; fp32 out + b3
  k_mgemm<64,2,false,true><<<GB, 256, 0, stream>>>(abf, Wp3, nullptr, nullptr, b3, nullptr, out);
}

// Round 12
// 257.838 us; speedup vs baseline: 1.8605x; 1.7276x over previous
//
#include <hip/hip_runtime.h>

#define NN 100000
#define EE 1600000
#define HN 128
#define OO 64
#define SB 256     // stats blocks
#define NBUCK 196  // ceil(NN/512), bucket = row >> 9
#define CH 4096    // edges per bucketing chunk
#define SLAB 16384 // fixed slab per bucket (mean 8192; overflow ~90 sigma -> nil)

typedef __attribute__((ext_vector_type(8))) short bf16x8;
typedef __attribute__((ext_vector_type(4))) float f32x4;

__device__ __forceinline__ unsigned short f2bf(float f){ // RNE bf16
  unsigned u = __float_as_uint(f);
  return (unsigned short)((u + 0x7FFFu + ((u >> 16) & 1u)) >> 16);
}
__device__ __forceinline__ float bflo(unsigned u){ return __uint_as_float(u << 16); }
__device__ __forceinline__ float bfhi(unsigned u){ return __uint_as_float(u & 0xFFFF0000u); }

// ---------------- bucket-scatter into fixed slabs, packed 4B/edge (+ weight pack) ----------------
__global__ __launch_bounds__(256) void k_bucket(const int* __restrict__ rows, const int* __restrict__ cols,
                                                int* __restrict__ pcur, unsigned* __restrict__ ebuf,
                                                const float* __restrict__ W1, const float* __restrict__ W2,
                                                const float* __restrict__ W3,
                                                unsigned short* __restrict__ Wp1, unsigned short* __restrict__ Wp2,
                                                unsigned short* __restrict__ Wp3){
  __shared__ int bc[NBUCK];
  __shared__ int boff[NBUCK];
  __shared__ int ccur[NBUCK];
  __shared__ int gbase[NBUCK];
  __shared__ uint2 stage[CH];
  const int t = threadIdx.x;
  const int base = blockIdx.x * CH;
  const int nval = min(CH, EE - base);

  for (int i = t; i < NBUCK; i += 256) bc[i] = 0;
  __syncthreads();

  int er[16], ec[16];
  #pragma unroll
  for (int j = 0; j < 16; ++j){
    int i = j*256 + t;
    if (i < nval){
      er[j] = rows[base+i]; ec[j] = cols[base+i];
      atomicAdd(&bc[er[j] >> 9], 1);
    } else er[j] = -1;
  }
  __syncthreads();

  if (t < 64){ // wave-0 scan of bc -> boff
    int lane = t, run = 0;
    for (int c = 0; c < NBUCK; c += 64){
      int i = c + lane;
      int v = (i < NBUCK) ? bc[i] : 0;
      int s = v;
      #pragma unroll
      for (int d = 1; d < 64; d <<= 1){ int u = __shfl_up(s, d); if (lane >= d) s += u; }
      if (i < NBUCK) boff[i] = run + s - v;
      run += __shfl(s, 63);
    }
  }
  __syncthreads();
  if (t < NBUCK){
    gbase[t] = bc[t] ? (t*SLAB + atomicAdd(&pcur[t], bc[t])) : 0;
    ccur[t]  = boff[t];
  }
  __syncthreads();
  #pragma unroll
  for (int j = 0; j < 16; ++j){
    if (er[j] >= 0){
      int b = er[j] >> 9;
      int p = atomicAdd(&ccur[b], 1);
      stage[p] = make_uint2((unsigned)er[j], (unsigned)ec[j]);
    }
  }
  __syncthreads();
  for (int i = t; i < nval; i += 256){
    uint2 e = stage[i];
    int b = (int)(e.x >> 9);
    unsigned pk = ((e.x & 511u) << 17) | e.y;       // packed: lrow(9b) | col(17b)
    ebuf[gbase[b] + (i - boff[b])] = pk;
  }

  // weight pack on first 20 blocks
  int b = blockIdx.x;
  if (b < 20){
    const float* W; unsigned short* Wp; int outc, i0;
    if (b < 8)      { W=W1; Wp=Wp1; outc=128; i0 = b*256; }
    else if (b < 16){ W=W2; Wp=Wp2; outc=128; i0 = (b-8)*256; }
    else            { W=W3; Wp=Wp3; outc=64;  i0 = (b-16)*256; }
    int i = i0 + t;
    if (i < 16*outc){
      int kb = i / outc, n = i - kb*outc;
      unsigned pk[4];
      #pragma unroll
      for (int jj = 0; jj < 4; ++jj){
        unsigned lo = f2bf(W[(size_t)(kb*8 + 2*jj)*outc + n]);
        unsigned hi = f2bf(W[(size_t)(kb*8 + 2*jj+1)*outc + n]);
        pk[jj] = lo | (hi << 16);
      }
      *reinterpret_cast<uint4*>(Wp + (size_t)i*8) = make_uint4(pk[0],pk[1],pk[2],pk[3]);
    }
  }
}

// ---------------- per-bucket CSR finalize (slab, packed) ----------------
__global__ __launch_bounds__(256) void k_build(const unsigned* __restrict__ ebuf,
                                               const int* __restrict__ pcur,
                                               int* __restrict__ row_start, int* __restrict__ cnt,
                                               float* __restrict__ dinv, int* __restrict__ csr_col){
  __shared__ int hist[512];
  __shared__ int cur[512];
  __shared__ int sCbase;
  const int b = blockIdx.x;
  const int row0 = b << 9;
  const int nrow = min(512, NN - row0);
  const int ebase = b * SLAB;
  const int ne = pcur[b];
  const int t = threadIdx.x;

  if (t < 64){ // csr base = sum pcur[0..b)
    int acc = 0;
    for (int i = t; i < b; i += 64) acc += pcur[i];
    #pragma unroll
    for (int d = 32; d; d >>= 1) acc += __shfl_xor(acc, d);
    if (t == 0) sCbase = acc;
  }
  for (int i = t; i < nrow; i += 256) hist[i] = 0;
  __syncthreads();
  for (int i = t; i < ne; i += 256)
    atomicAdd(&hist[ebuf[ebase+i] >> 17], 1);
  __syncthreads();

  if (t < 64){
    int lane = t, run = 0;
    for (int c = 0; c < nrow; c += 64){
      int i = c + lane;
      int v = (i < nrow) ? hist[i] : 0;
      int s = v;
      #pragma unroll
      for (int d = 1; d < 64; d <<= 1){ int u = __shfl_up(s, d); if (lane >= d) s += u; }
      if (i < nrow) cur[i] = run + s - v;
      run += __shfl(s, 63);
    }
  }
  __syncthreads();
  const int cbase = sCbase;
  for (int i = t; i < nrow; i += 256){
    int h = hist[i];
    int r = row0 + i;
    cnt[r] = h;
    dinv[r] = rsqrtf((float)(h+1));
    row_start[r] = cbase + cur[i];
    cur[i] += cbase;
  }
  __syncthreads();
  for (int i = t; i < ne; i += 256){
    unsigned e = ebuf[ebase+i];
    int p = atomicAdd(&cur[e >> 17], 1);
    csr_col[p] = (int)(e & 0x1FFFFu);
  }
}

// ---------------- aggregation over bf16 rows pre-scaled by dinv (R5 form, bf16 out) ----------------
__global__ __launch_bounds__(256) void k_agg(const unsigned* __restrict__ h,
                                             const int* __restrict__ row_start,
                                             const int* __restrict__ cnt,
                                             const int* __restrict__ col,
                                             const float* __restrict__ dinv,
                                             const float* __restrict__ bias,
                                             unsigned* __restrict__ outv){
  int wib  = __builtin_amdgcn_readfirstlane((int)(threadIdx.x >> 6));  // SGPR wave id
  int wid  = blockIdx.x*4 + wib;
  int lane = threadIdx.x & 63;
  if (wid >= NN) return;
  int s = row_start[wid];           // scalar loads (wid uniform)
  int e = s + cnt[wid];
  float dr = dinv[wid];
  const unsigned* hp = h + lane;
  float ax, ay;
  {
    unsigned u = hp[(size_t)wid*64];
    ax = bflo(u); ay = bfhi(u);
  }
  int p = s;
  for (; p+7 < e; p += 8){           // 8 outstanding gathers
    unsigned uu[8];
    #pragma unroll
    for (int j=0;j<8;++j) uu[j] = hp[(size_t)col[p+j]*64];
    #pragma unroll
    for (int j=0;j<8;++j){ ax += bflo(uu[j]); ay += bfhi(uu[j]); }
  }
  for (; p+3 < e; p += 4){
    unsigned uu[4];
    #pragma unroll
    for (int j=0;j<4;++j) uu[j] = hp[(size_t)col[p+j]*64];
    #pragma unroll
    for (int j=0;j<4;++j){ ax += bflo(uu[j]); ay += bfhi(uu[j]); }
  }
  for (; p < e; ++p){
    unsigned u = hp[(size_t)col[p]*64];
    ax += bflo(u); ay += bfhi(u);
  }
  float2 bb = *reinterpret_cast<const float2*>(bias + 2*lane);
  float ox = ax*dr + bb.x, oy = ay*dr + bb.y;
  outv[(size_t)wid*64 + lane] = (unsigned)f2bf(ox) | ((unsigned)f2bf(oy) << 16);
}

// ---------------- MFMA GEMM: C[N x OUTC] = xform(A[N x 128]) * W (W direct from global) ----------------
// XFORM: 0 none, 1 relu(a*scale+shift) (BN), 2 relu
// ABF16: A rows are packed bf16 (64 uints); else fp32
// BF16OUT: write bf16 rows scaled by dinv[row]; else fp32 + bias
template<int OUTC, int XFORM, bool BF16OUT, bool ABF16>
__global__ __launch_bounds__(256) void k_mgemm(const void* __restrict__ Av,
                                               const unsigned short* __restrict__ Wp,
                                               const float* __restrict__ scale,
                                               const float* __restrict__ shiftv,
                                               const float* __restrict__ bias,
                                               const float* __restrict__ dinv,
                                               void* __restrict__ Cv){
  __shared__ char AsB[32768];   // 128 rows x 256 B bf16, XOR-swizzled
  const int t = threadIdx.x;
  const int row0 = blockIdx.x * 128;

  if constexpr (ABF16){ // stage bf16 A: XFORM in fp32, repack
    const uint4* A = (const uint4*)Av;   // 16 uint4 per row
    const int c8 = t & 15;
    const int k0 = c8*8;
    float sc[8], sh[8];
    if (XFORM == 1){
      #pragma unroll
      for (int j=0;j<8;++j){ sc[j]=scale[k0+j]; sh[j]=shiftv[k0+j]; }
    }
    #pragma unroll
    for (int g = 0; g < 8; ++g){
      int f = g*256 + t;
      int r = f >> 4;
      int row = row0 + r;
      int rc = row < NN ? row : NN-1;
      uint4 q = A[(size_t)rc*16 + c8];
      float vf[8] = { bflo(q.x),bfhi(q.x),bflo(q.y),bfhi(q.y),
                      bflo(q.z),bfhi(q.z),bflo(q.w),bfhi(q.w) };
      if (XFORM == 1){
        #pragma unroll
        for (int j=0;j<8;++j) vf[j] = fmaxf(fmaf(vf[j], sc[j], sh[j]), 0.f);
      } else if (XFORM == 2){
        #pragma unroll
        for (int j=0;j<8;++j) vf[j] = fmaxf(vf[j], 0.f);
      }
      unsigned pk[4];
      #pragma unroll
      for (int j=0;j<4;++j)
        pk[j] = (unsigned)f2bf(vf[2*j]) | ((unsigned)f2bf(vf[2*j+1]) << 16);
      int boff = (c8*16) ^ ((r & 7) << 4);
      *reinterpret_cast<uint4*>(AsB + r*256 + boff) = make_uint4(pk[0],pk[1],pk[2],pk[3]);
    }
  } else { // stage fp32 A -> bf16
    const float* A = (const float*)Av;
    #pragma unroll
    for (int g = 0; g < 16; ++g){
      int f = g*256 + t;
      int r = f >> 5;
      int c4 = f & 31;
      int row = row0 + r;
      int rc = row < NN ? row : NN-1;
      float4 v = *reinterpret_cast<const float4*>(A + (size_t)rc*HN + c4*4);
      if (XFORM == 2){
        v.x = fmaxf(v.x, 0.f); v.y = fmaxf(v.y, 0.f);
        v.z = fmaxf(v.z, 0.f); v.w = fmaxf(v.w, 0.f);
      }
      unsigned p0 = (unsigned)f2bf(v.x) | ((unsigned)f2bf(v.y) << 16);
      unsigned p1 = (unsigned)f2bf(v.z) | ((unsigned)f2bf(v.w) << 16);
      int boff = (c4*8) ^ ((r & 7) << 4);
      *reinterpret_cast<uint2*>(AsB + r*256 + boff) = make_uint2(p0, p1);
    }
  }
  __syncthreads();

  const int wv = t >> 6;
  const int l  = t & 63;
  const int lm = l & 15;
  const int lk = l >> 4;
  constexpr int NF = OUTC/16;

  f32x4 acc[2][NF];
  #pragma unroll
  for (int mi=0;mi<2;++mi)
    #pragma unroll
    for (int ni=0;ni<NF;++ni) acc[mi][ni] = (f32x4){0.f,0.f,0.f,0.f};

  const bf16x8* WpV = reinterpret_cast<const bf16x8*>(Wp);

  #pragma unroll
  for (int ks = 0; ks < 4; ++ks){
    bf16x8 af[2];
    #pragma unroll
    for (int mi=0;mi<2;++mi){
      int R = wv*32 + mi*16 + lm;
      int boff = (ks*64 + lk*16) ^ ((R & 7) << 4);
      af[mi] = *reinterpret_cast<const bf16x8*>(AsB + R*256 + boff);
    }
    int kb = ks*4 + lk;
    #pragma unroll
    for (int ni=0;ni<NF;++ni){
      int n = ni*16 + lm;
      bf16x8 bfr = WpV[kb*OUTC + n];         // global, coalesced, L1/L2-hot (32 KB)
      acc[0][ni] = __builtin_amdgcn_mfma_f32_16x16x32_bf16(af[0], bfr, acc[0][ni], 0,0,0);
      acc[1][ni] = __builtin_amdgcn_mfma_f32_16x16x32_bf16(af[1], bfr, acc[1][ni], 0,0,0);
    }
  }

  // epilogue: D frag (mi,ni): row = wv*32+mi*16+lk*4+j, col = ni*16+lm
  #pragma unroll
  for (int mi=0;mi<2;++mi){
    #pragma unroll
    for (int j=0;j<4;++j){
      int grow = row0 + wv*32 + mi*16 + lk*4 + j;
      if (grow >= NN) continue;
      if constexpr (BF16OUT){
        float dr = dinv[grow];
        unsigned short* po = (unsigned short*)Cv + (size_t)grow*OUTC;
        #pragma unroll
        for (int ni=0;ni<NF;++ni)
          po[ni*16 + lm] = f2bf(acc[mi][ni][j] * dr);
      } else {
        float* po = (float*)Cv + (size_t)grow*OUTC;
        #pragma unroll
        for (int ni=0;ni<NF;++ni)
          po[ni*16 + lm] = acc[mi][ni][j] + bias[ni*16 + lm];
      }
    }
  }
}

// ---------------- BN stats over bf16 rows (deterministic two-stage) ----------------
__global__ __launch_bounds__(256) void k_stats(const unsigned* __restrict__ a,
                                               float* __restrict__ ps, float* __restrict__ pq){
  __shared__ float l0[256], l1[256], m0[256], m1[256];
  int c = threadIdx.x & 63;
  int grp = threadIdx.x >> 6;
  float s0=0.f,s1=0.f,q0=0.f,q1=0.f;
  for (int r = blockIdx.x*4 + grp; r < NN; r += SB*4){
    unsigned u = a[(size_t)r*64 + c];
    float v0 = bflo(u), v1 = bfhi(u);
    s0 += v0; s1 += v1; q0 = fmaf(v0,v0,q0); q1 = fmaf(v1,v1,q1);
  }
  l0[threadIdx.x]=s0; l1[threadIdx.x]=s1; m0[threadIdx.x]=q0; m1[threadIdx.x]=q1;
  __syncthreads();
  if (grp==0){
    #pragma unroll
    for (int g=1;g<4;++g){ s0+=l0[g*64+c]; s1+=l1[g*64+c]; q0+=m0[g*64+c]; q1+=m1[g*64+c]; }
    ps[blockIdx.x*128 + 2*c]   = s0; ps[blockIdx.x*128 + 2*c+1] = s1;
    pq[blockIdx.x*128 + 2*c]   = q0; pq[blockIdx.x*128 + 2*c+1] = q1;
  }
}

__global__ __launch_bounds__(128) void k_bnfinal(const float* __restrict__ ps, const float* __restrict__ pq,
                                                 const float* __restrict__ gamma, const float* __restrict__ beta,
                                                 float* __restrict__ scale, float* __restrict__ shiftv){
  int c = threadIdx.x;
  float s=0.f, q=0.f;
  for (int b=0;b<SB;b++){ s += ps[b*128+c]; q += pq[b*128+c]; }
  float mean = s * (1.0f/NN);
  float var  = q * (1.0f/NN) - mean*mean;
  float inv  = rsqrtf(var + 1e-5f);
  float sc = gamma[c]*inv;
  scale[c]  = sc;
  shiftv[c] = beta[c] - mean*sc;
}

// ---------------- launch ----------------
extern "C" void kernel_launch(void* const* d_in, const int* in_sizes, int n_in,
                              void* d_out, int out_size, void* d_ws, size_t ws_size,
                              hipStream_t stream) {
  const float* x      = (const float*)d_in[0];
  const int*   ei     = (const int*)d_in[1];
  const int*   rows   = ei;
  const int*   cols   = ei + EE;
  const float* W1     = (const float*)d_in[2];
  const float* b1     = (const float*)d_in[3];
  const float* gamma1 = (const float*)d_in[4];
  const float* beta1  = (const float*)d_in[5];
  const float* W2     = (const float*)d_in[6];
  const float* b2     = (const float*)d_in[7];
  const float* W3     = (const float*)d_in[8];
  const float* b3     = (const float*)d_in[9];
  float* out = (float*)d_out;

  char* w = (char*)d_ws;
  float* buf0      = (float*)w; w += (size_t)NN*HN*4;   // ebuf slabs (12.8MB packed) then hbf bf16
  float* buf1      = (float*)w; w += (size_t)NN*HN*4;   // abf bf16
  int*   csr_col   = (int*)w;   w += (size_t)EE*4;
  int*   row_start = (int*)w;   w += (size_t)NN*4;
  int*   cnt       = (int*)w;   w += (size_t)NN*4;
  float* dinv      = (float*)w; w += (size_t)NN*4;
  float* ps        = (float*)w; w += (size_t)SB*128*4;
  float* pq        = (float*)w; w += (size_t)SB*128*4;
  float* scale     = (float*)w; w += 1024;
  float* shiftv    = (float*)w; w += 1024;
  int*   scr0      = (int*)w;   w += 4096;   // pcur[256]
  unsigned short* Wp1 = (unsigned short*)w; w += 128*128*2;
  unsigned short* Wp2 = (unsigned short*)w; w += 128*128*2;
  unsigned short* Wp3 = (unsigned short*)w; w += 128*64*2;
  int* pcur = scr0;
  unsigned* ebuf = (unsigned*)buf0;    // dead before mgemm1 writes hbf
  unsigned* hbf  = (unsigned*)buf0;    // bf16 h rows (64 uints/row)
  unsigned* abf  = (unsigned*)buf1;    // bf16 agg rows

  (void)hipMemsetAsync(scr0, 0, 4096, stream);

  const int CB = (EE + CH - 1)/CH, GB = (NN+127)/128, AB = NN/4;

  k_bucket<<<CB, 256, 0, stream>>>(rows, cols, pcur, ebuf, W1, W2, W3, Wp1, Wp2, Wp3);
  k_build <<<NBUCK, 256, 0, stream>>>(ebuf, pcur, row_start, cnt, dinv, csr_col);

  // layer 1: h1' = bf16((x@W1)*dinv); agg -> abf (bf16, +b1); BN stats
  k_mgemm<128,0,true,false><<<GB, 256, 0, stream>>>(x, Wp1, nullptr, nullptr, nullptr, dinv, hbf);
  k_agg<<<AB, 256, 0, stream>>>(hbf, row_start, cnt, csr_col, dinv, b1, abf);
  k_stats<<<SB, 256, 0, stream>>>(abf, ps, pq);
  k_bnfinal<<<1, 128, 0, stream>>>(ps, pq, gamma1, beta1, scale, shiftv);

  // layer 2: BN+relu fused into staging (bf16 A); h2' bf16
  k_mgemm<128,1,true,true><<<GB, 256, 0, stream>>>(abf, Wp2, scale, shiftv, nullptr, dinv, hbf);
  k_agg<<<AB, 256, 0, stream>>>(hbf, row_start, cnt, csr_col, dinv, b2, abf);

  // layer 3: relu fused into staging (bf16 A), fp32 out + b3
  k_mgemm<64,2,false,true><<<GB, 256, 0, stream>>>(abf, Wp3, nullptr, nullptr, b3, nullptr, out);
}

// Round 13
// 240.156 us; speedup vs baseline: 1.9975x; 1.0736x over previous
//
#include <hip/hip_runtime.h>

#define NN 100000
#define EE 1600000
#define HN 128
#define OO 64
#define SB 256     // stats blocks
#define NBUCK 196  // ceil(NN/512), bucket = row >> 9
#define CH 4096    // edges per bucketing chunk
#define SLAB 16384 // fixed slab per bucket (mean 8192; overflow ~90 sigma -> nil)

typedef __attribute__((ext_vector_type(8))) short bf16x8;
typedef __attribute__((ext_vector_type(4))) float f32x4;

__device__ __forceinline__ unsigned short f2bf(float f){ // RNE bf16
  unsigned u = __float_as_uint(f);
  return (unsigned short)((u + 0x7FFFu + ((u >> 16) & 1u)) >> 16);
}
__device__ __forceinline__ float bflo(unsigned u){ return __uint_as_float(u << 16); }
__device__ __forceinline__ float bfhi(unsigned u){ return __uint_as_float(u & 0xFFFF0000u); }

#define CB ((EE + CH - 1)/CH)   // 391 bucket blocks
#define GB ((NN + 127)/128)     // 782 gemm blocks

// ---------------- fused: bucket-scatter (+W2/W3 pack) || mgemm1 (h1 = bf16(x@W1), UNSCALED) ----------------
__global__ __launch_bounds__(256) void k_fused(const int* __restrict__ rows, const int* __restrict__ cols,
                                               int* __restrict__ pcur, unsigned* __restrict__ ebuf,
                                               const float* __restrict__ x, const float* __restrict__ W1,
                                               const float* __restrict__ W2, const float* __restrict__ W3,
                                               unsigned short* __restrict__ Wp2, unsigned short* __restrict__ Wp3,
                                               unsigned* __restrict__ hbf){
  __shared__ char lds[65536];
  const int t = threadIdx.x;

  if (blockIdx.x < CB){
    // ================= bucket path =================
    int* bc    = (int*)lds;            // [256]
    int* boff  = (int*)(lds + 1024);
    int* ccur  = (int*)(lds + 2048);
    int* gbase = (int*)(lds + 3072);
    uint2* stage = (uint2*)(lds + 4096);  // 32 KB
    const int base = blockIdx.x * CH;
    const int nval = min(CH, EE - base);

    for (int i = t; i < NBUCK; i += 256) bc[i] = 0;
    __syncthreads();

    int er[16], ec[16];
    #pragma unroll
    for (int j = 0; j < 16; ++j){
      int i = j*256 + t;
      if (i < nval){
        er[j] = rows[base+i]; ec[j] = cols[base+i];
        atomicAdd(&bc[er[j] >> 9], 1);
      } else er[j] = -1;
    }
    __syncthreads();

    if (t < 64){ // wave-0 scan of bc -> boff
      int lane = t, run = 0;
      for (int c = 0; c < NBUCK; c += 64){
        int i = c + lane;
        int v = (i < NBUCK) ? bc[i] : 0;
        int s = v;
        #pragma unroll
        for (int d = 1; d < 64; d <<= 1){ int u = __shfl_up(s, d); if (lane >= d) s += u; }
        if (i < NBUCK) boff[i] = run + s - v;
        run += __shfl(s, 63);
      }
    }
    __syncthreads();
    if (t < NBUCK){
      gbase[t] = bc[t] ? (t*SLAB + atomicAdd(&pcur[t], bc[t])) : 0;
      ccur[t]  = boff[t];
    }
    __syncthreads();
    #pragma unroll
    for (int j = 0; j < 16; ++j){
      if (er[j] >= 0){
        int b = er[j] >> 9;
        int p = atomicAdd(&ccur[b], 1);
        stage[p] = make_uint2((unsigned)er[j], (unsigned)ec[j]);
      }
    }
    __syncthreads();
    for (int i = t; i < nval; i += 256){
      uint2 e = stage[i];
      int b = (int)(e.x >> 9);
      unsigned pk = ((e.x & 511u) << 17) | e.y;   // packed: lrow(9b) | col(17b)
      ebuf[gbase[b] + (i - boff[b])] = pk;
    }

    // W2/W3 pack on blocks 0..11 (consumed by later dispatches)
    int b = blockIdx.x;
    if (b < 12){
      const float* W = (b < 8) ? W2 : W3;
      unsigned short* Wp = (b < 8) ? Wp2 : Wp3;
      int outc = (b < 8) ? 128 : 64;
      int i0 = (b < 8) ? b*256 : (b-8)*256;
      int i = i0 + t;
      if (i < 16*outc){
        int kb = i / outc, n = i - kb*outc;
        unsigned pk[4];
        #pragma unroll
        for (int jj = 0; jj < 4; ++jj){
          unsigned lo = f2bf(W[(size_t)(kb*8 + 2*jj)*outc + n]);
          unsigned hi = f2bf(W[(size_t)(kb*8 + 2*jj+1)*outc + n]);
          pk[jj] = lo | (hi << 16);
        }
        *reinterpret_cast<uint4*>(Wp + (size_t)i*8) = make_uint4(pk[0],pk[1],pk[2],pk[3]);
      }
    }
  } else {
    // ================= mgemm1 path: h1 = bf16(x @ W1), unscaled =================
    char* AsB = lds;            // 32 KB A tile
    char* WsB = lds + 32768;    // 32 KB W tile [kb][n][8]
    const int row0 = (int)(blockIdx.x - CB) * 128;

    { // stage W1 fp32 -> bf16 packed (L2-hot after first block)
      #pragma unroll
      for (int it = 0; it < 8; ++it){
        int i = it*256 + t;            // 0..2047
        int kb = i >> 7, n = i & 127;
        unsigned pk[4];
        #pragma unroll
        for (int j = 0; j < 4; ++j){
          unsigned lo = f2bf(W1[(size_t)(kb*8 + 2*j)*128 + n]);
          unsigned hi = f2bf(W1[(size_t)(kb*8 + 2*j+1)*128 + n]);
          pk[j] = lo | (hi << 16);
        }
        *reinterpret_cast<uint4*>(WsB + (size_t)i*16) = make_uint4(pk[0],pk[1],pk[2],pk[3]);
      }
    }
    { // stage A (fp32 x) -> bf16 swizzled
      #pragma unroll
      for (int g = 0; g < 16; ++g){
        int f = g*256 + t;
        int r = f >> 5;
        int c4 = f & 31;
        int row = row0 + r;
        int rc = row < NN ? row : NN-1;
        float4 v = *reinterpret_cast<const float4*>(x + (size_t)rc*HN + c4*4);
        unsigned p0 = (unsigned)f2bf(v.x) | ((unsigned)f2bf(v.y) << 16);
        unsigned p1 = (unsigned)f2bf(v.z) | ((unsigned)f2bf(v.w) << 16);
        int boffb = (c4*8) ^ ((r & 7) << 4);
        *reinterpret_cast<uint2*>(AsB + r*256 + boffb) = make_uint2(p0, p1);
      }
    }
    __syncthreads();

    const int wv = t >> 6;
    const int l  = t & 63;
    const int lm = l & 15;
    const int lk = l >> 4;

    f32x4 acc[2][8];
    #pragma unroll
    for (int mi=0;mi<2;++mi)
      #pragma unroll
      for (int ni=0;ni<8;++ni) acc[mi][ni] = (f32x4){0.f,0.f,0.f,0.f};

    #pragma unroll
    for (int ks = 0; ks < 4; ++ks){
      bf16x8 af[2];
      #pragma unroll
      for (int mi=0;mi<2;++mi){
        int R = wv*32 + mi*16 + lm;
        int boffb = (ks*64 + lk*16) ^ ((R & 7) << 4);
        af[mi] = *reinterpret_cast<const bf16x8*>(AsB + R*256 + boffb);
      }
      int kb = ks*4 + lk;
      #pragma unroll
      for (int ni=0;ni<8;++ni){
        int n = ni*16 + lm;
        bf16x8 bfr = *reinterpret_cast<const bf16x8*>(WsB + (size_t)(kb*128 + n)*16);
        acc[0][ni] = __builtin_amdgcn_mfma_f32_16x16x32_bf16(af[0], bfr, acc[0][ni], 0,0,0);
        acc[1][ni] = __builtin_amdgcn_mfma_f32_16x16x32_bf16(af[1], bfr, acc[1][ni], 0,0,0);
      }
    }

    #pragma unroll
    for (int mi=0;mi<2;++mi){
      #pragma unroll
      for (int j=0;j<4;++j){
        int grow = row0 + wv*32 + mi*16 + lk*4 + j;
        if (grow >= NN) continue;
        unsigned short* po = (unsigned short*)hbf + (size_t)grow*HN;
        #pragma unroll
        for (int ni=0;ni<8;++ni)
          po[ni*16 + lm] = f2bf(acc[mi][ni][j]);   // UNSCALED
      }
    }
  }
}

// ---------------- per-bucket CSR finalize (slab, packed) ----------------
__global__ __launch_bounds__(256) void k_build(const unsigned* __restrict__ ebuf,
                                               const int* __restrict__ pcur,
                                               int* __restrict__ row_start, int* __restrict__ cnt,
                                               float* __restrict__ dinv, int* __restrict__ csr_col){
  __shared__ int hist[512];
  __shared__ int cur[512];
  __shared__ int sCbase;
  const int b = blockIdx.x;
  const int row0 = b << 9;
  const int nrow = min(512, NN - row0);
  const int ebase = b * SLAB;
  const int ne = pcur[b];
  const int t = threadIdx.x;

  if (t < 64){ // csr base = sum pcur[0..b)
    int acc = 0;
    for (int i = t; i < b; i += 64) acc += pcur[i];
    #pragma unroll
    for (int d = 32; d; d >>= 1) acc += __shfl_xor(acc, d);
    if (t == 0) sCbase = acc;
  }
  for (int i = t; i < nrow; i += 256) hist[i] = 0;
  __syncthreads();
  for (int i = t; i < ne; i += 256)
    atomicAdd(&hist[ebuf[ebase+i] >> 17], 1);
  __syncthreads();

  if (t < 64){
    int lane = t, run = 0;
    for (int c = 0; c < nrow; c += 64){
      int i = c + lane;
      int v = (i < nrow) ? hist[i] : 0;
      int s = v;
      #pragma unroll
      for (int d = 1; d < 64; d <<= 1){ int u = __shfl_up(s, d); if (lane >= d) s += u; }
      if (i < nrow) cur[i] = run + s - v;
      run += __shfl(s, 63);
    }
  }
  __syncthreads();
  const int cbase = sCbase;
  for (int i = t; i < nrow; i += 256){
    int h = hist[i];
    int r = row0 + i;
    cnt[r] = h;
    dinv[r] = rsqrtf((float)(h+1));
    row_start[r] = cbase + cur[i];
    cur[i] += cbase;
  }
  __syncthreads();
  for (int i = t; i < ne; i += 256){
    unsigned e = ebuf[ebase+i];
    int p = atomicAdd(&cur[e >> 17], 1);
    csr_col[p] = (int)(e & 0x1FFFFu);
  }
}

// ---------------- agg layer 1: dinv-weighted gather over UNSCALED bf16 h ----------------
// out[r] = dr*(dr*h[r] + sum_c dinv[c]*h[c]) + b1   (bf16 out)
__global__ __launch_bounds__(256) void k_aggd(const unsigned* __restrict__ h,
                                              const int* __restrict__ row_start,
                                              const int* __restrict__ cnt,
                                              const int* __restrict__ col,
                                              const float* __restrict__ dinv,
                                              const float* __restrict__ bias,
                                              unsigned* __restrict__ outv){
  int wib  = __builtin_amdgcn_readfirstlane((int)(threadIdx.x >> 6));
  int wid  = blockIdx.x*4 + wib;
  int lane = threadIdx.x & 63;
  if (wid >= NN) return;
  int s = row_start[wid];
  int e = s + cnt[wid];
  float dr = dinv[wid];
  const unsigned* hp = h + lane;
  float ax, ay;
  {
    unsigned u = hp[(size_t)wid*64];
    ax = dr*bflo(u); ay = dr*bfhi(u);
  }
  int p = s;
  for (; p+7 < e; p += 8){
    unsigned uu[8]; float dd[8];
    #pragma unroll
    for (int j=0;j<8;++j){ int c = col[p+j]; dd[j] = dinv[c]; uu[j] = hp[(size_t)c*64]; }
    #pragma unroll
    for (int j=0;j<8;++j){ ax = fmaf(bflo(uu[j]), dd[j], ax); ay = fmaf(bfhi(uu[j]), dd[j], ay); }
  }
  for (; p+3 < e; p += 4){
    unsigned uu[4]; float dd[4];
    #pragma unroll
    for (int j=0;j<4;++j){ int c = col[p+j]; dd[j] = dinv[c]; uu[j] = hp[(size_t)c*64]; }
    #pragma unroll
    for (int j=0;j<4;++j){ ax = fmaf(bflo(uu[j]), dd[j], ax); ay = fmaf(bfhi(uu[j]), dd[j], ay); }
  }
  for (; p < e; ++p){
    int c = col[p]; float d = dinv[c];
    unsigned u = hp[(size_t)c*64];
    ax = fmaf(bflo(u), d, ax); ay = fmaf(bfhi(u), d, ay);
  }
  float2 bb = *reinterpret_cast<const float2*>(bias + 2*lane);
  float ox = ax*dr + bb.x, oy = ay*dr + bb.y;
  outv[(size_t)wid*64 + lane] = (unsigned)f2bf(ox) | ((unsigned)f2bf(oy) << 16);
}

// ---------------- fused: agg layer-2 (pre-scaled h2') + relu + GEMM3 + b3 -> out fp32 ----------------
__global__ __launch_bounds__(256) void k_aggmm(const unsigned* __restrict__ h,
                                               const int* __restrict__ row_start,
                                               const int* __restrict__ cnt,
                                               const int* __restrict__ col,
                                               const float* __restrict__ dinv,
                                               const float* __restrict__ b2,
                                               const unsigned short* __restrict__ Wp3,
                                               const float* __restrict__ b3,
                                               float* __restrict__ out){
  __shared__ char AsB[32*256];   // 32 rows x 256 B bf16, XOR-swizzled
  const int t = threadIdx.x;
  const int wv = __builtin_amdgcn_readfirstlane(t >> 6);
  const int lane = t & 63;
  const int tile = blockIdx.x * 32;

  for (int k = 0; k < 8; ++k){
    int wid = tile + wv*8 + k;          // NN = 3125*32
    int s = row_start[wid];
    int e = s + cnt[wid];
    float dr = dinv[wid];
    const unsigned* hp = h + lane;
    float ax, ay;
    { unsigned u = hp[(size_t)wid*64]; ax = bflo(u); ay = bfhi(u); }
    int p = s;
    for (; p+7 < e; p += 8){
      unsigned uu[8];
      #pragma unroll
      for (int j=0;j<8;++j) uu[j] = hp[(size_t)col[p+j]*64];
      #pragma unroll
      for (int j=0;j<8;++j){ ax += bflo(uu[j]); ay += bfhi(uu[j]); }
    }
    for (; p+3 < e; p += 4){
      unsigned uu[4];
      #pragma unroll
      for (int j=0;j<4;++j) uu[j] = hp[(size_t)col[p+j]*64];
      #pragma unroll
      for (int j=0;j<4;++j){ ax += bflo(uu[j]); ay += bfhi(uu[j]); }
    }
    for (; p < e; ++p){
      unsigned u = hp[(size_t)col[p]*64];
      ax += bflo(u); ay += bfhi(u);
    }
    float2 bb = *reinterpret_cast<const float2*>(b2 + 2*lane);
    float ox = fmaxf(ax*dr + bb.x, 0.f);   // relu fused
    float oy = fmaxf(ay*dr + bb.y, 0.f);
    int r = wv*8 + k;
    unsigned pk = (unsigned)f2bf(ox) | ((unsigned)f2bf(oy) << 16);
    *reinterpret_cast<unsigned*>(AsB + r*256 + ((lane*4) ^ ((r & 7) << 4))) = pk;
  }
  __syncthreads();

  const int lm = lane & 15;
  const int lk = lane >> 4;
  const int mb  = wv >> 1;
  const int nb2 = (wv & 1) * 2;
  f32x4 acc[2] = {(f32x4){0.f,0.f,0.f,0.f},(f32x4){0.f,0.f,0.f,0.f}};
  const bf16x8* WpV = reinterpret_cast<const bf16x8*>(Wp3);

  #pragma unroll
  for (int ks = 0; ks < 4; ++ks){
    int R = mb*16 + lm;
    bf16x8 af = *reinterpret_cast<const bf16x8*>(AsB + R*256 + ((ks*64 + lk*16) ^ ((R & 7) << 4)));
    int kb = ks*4 + lk;
    #pragma unroll
    for (int ni = 0; ni < 2; ++ni){
      int n = (nb2+ni)*16 + lm;
      bf16x8 bfr = WpV[kb*OO + n];
      acc[ni] = __builtin_amdgcn_mfma_f32_16x16x32_bf16(af, bfr, acc[ni], 0,0,0);
    }
  }

  #pragma unroll
  for (int ni = 0; ni < 2; ++ni){
    int gcol = (nb2+ni)*16 + lm;
    float bb = b3[gcol];
    #pragma unroll
    for (int j = 0; j < 4; ++j){
      int grow = tile + mb*16 + lk*4 + j;
      out[(size_t)grow*OO + gcol] = acc[ni][j] + bb;
    }
  }
}

// ---------------- MFMA GEMM2: h2' = bf16(dinv * (BNrelu(abf) @ W2)) ----------------
__global__ __launch_bounds__(256) void k_mgemm2(const unsigned* __restrict__ Av,
                                                const unsigned short* __restrict__ Wp,
                                                const float* __restrict__ scale,
                                                const float* __restrict__ shiftv,
                                                const float* __restrict__ dinv,
                                                unsigned* __restrict__ Cv){
  __shared__ char AsB[32768];
  const int t = threadIdx.x;
  const int row0 = blockIdx.x * 128;

  { // stage bf16 A with BN+relu
    const uint4* A = (const uint4*)Av;   // 16 uint4 per row
    const int c8 = t & 15;
    const int k0 = c8*8;
    float sc[8], sh[8];
    #pragma unroll
    for (int j=0;j<8;++j){ sc[j]=scale[k0+j]; sh[j]=shiftv[k0+j]; }
    #pragma unroll
    for (int g = 0; g < 8; ++g){
      int f = g*256 + t;
      int r = f >> 4;
      int row = row0 + r;
      int rc = row < NN ? row : NN-1;
      uint4 q = A[(size_t)rc*16 + c8];
      float vf[8] = { bflo(q.x),bfhi(q.x),bflo(q.y),bfhi(q.y),
                      bflo(q.z),bfhi(q.z),bflo(q.w),bfhi(q.w) };
      #pragma unroll
      for (int j=0;j<8;++j) vf[j] = fmaxf(fmaf(vf[j], sc[j], sh[j]), 0.f);
      unsigned pk[4];
      #pragma unroll
      for (int j=0;j<4;++j)
        pk[j] = (unsigned)f2bf(vf[2*j]) | ((unsigned)f2bf(vf[2*j+1]) << 16);
      int boffb = (c8*16) ^ ((r & 7) << 4);
      *reinterpret_cast<uint4*>(AsB + r*256 + boffb) = make_uint4(pk[0],pk[1],pk[2],pk[3]);
    }
  }
  __syncthreads();

  const int wv = t >> 6;
  const int l  = t & 63;
  const int lm = l & 15;
  const int lk = l >> 4;

  f32x4 acc[2][8];
  #pragma unroll
  for (int mi=0;mi<2;++mi)
    #pragma unroll
    for (int ni=0;ni<8;++ni) acc[mi][ni] = (f32x4){0.f,0.f,0.f,0.f};

  const bf16x8* WpV = reinterpret_cast<const bf16x8*>(Wp);

  #pragma unroll
  for (int ks = 0; ks < 4; ++ks){
    bf16x8 af[2];
    #pragma unroll
    for (int mi=0;mi<2;++mi){
      int R = wv*32 + mi*16 + lm;
      int boffb = (ks*64 + lk*16) ^ ((R & 7) << 4);
      af[mi] = *reinterpret_cast<const bf16x8*>(AsB + R*256 + boffb);
    }
    int kb = ks*4 + lk;
    #pragma unroll
    for (int ni=0;ni<8;++ni){
      int n = ni*16 + lm;
      bf16x8 bfr = WpV[kb*128 + n];
      acc[0][ni] = __builtin_amdgcn_mfma_f32_16x16x32_bf16(af[0], bfr, acc[0][ni], 0,0,0);
      acc[1][ni] = __builtin_amdgcn_mfma_f32_16x16x32_bf16(af[1], bfr, acc[1][ni], 0,0,0);
    }
  }

  #pragma unroll
  for (int mi=0;mi<2;++mi){
    #pragma unroll
    for (int j=0;j<4;++j){
      int grow = row0 + wv*32 + mi*16 + lk*4 + j;
      if (grow >= NN) continue;
      float dr = dinv[grow];
      unsigned short* po = (unsigned short*)Cv + (size_t)grow*HN;
      #pragma unroll
      for (int ni=0;ni<8;++ni)
        po[ni*16 + lm] = f2bf(acc[mi][ni][j] * dr);
    }
  }
}

// ---------------- BN stats over bf16 rows (deterministic two-stage) ----------------
__global__ __launch_bounds__(256) void k_stats(const unsigned* __restrict__ a,
                                               float* __restrict__ ps, float* __restrict__ pq){
  __shared__ float l0[256], l1[256], m0[256], m1[256];
  int c = threadIdx.x & 63;
  int grp = threadIdx.x >> 6;
  float s0=0.f,s1=0.f,q0=0.f,q1=0.f;
  for (int r = blockIdx.x*4 + grp; r < NN; r += SB*4){
    unsigned u = a[(size_t)r*64 + c];
    float v0 = bflo(u), v1 = bfhi(u);
    s0 += v0; s1 += v1; q0 = fmaf(v0,v0,q0); q1 = fmaf(v1,v1,q1);
  }
  l0[threadIdx.x]=s0; l1[threadIdx.x]=s1; m0[threadIdx.x]=q0; m1[threadIdx.x]=q1;
  __syncthreads();
  if (grp==0){
    #pragma unroll
    for (int g=1;g<4;++g){ s0+=l0[g*64+c]; s1+=l1[g*64+c]; q0+=m0[g*64+c]; q1+=m1[g*64+c]; }
    ps[blockIdx.x*128 + 2*c]   = s0; ps[blockIdx.x*128 + 2*c+1] = s1;
    pq[blockIdx.x*128 + 2*c]   = q0; pq[blockIdx.x*128 + 2*c+1] = q1;
  }
}

__global__ __launch_bounds__(128) void k_bnfinal(const float* __restrict__ ps, const float* __restrict__ pq,
                                                 const float* __restrict__ gamma, const float* __restrict__ beta,
                                                 float* __restrict__ scale, float* __restrict__ shiftv){
  int c = threadIdx.x;
  float s=0.f, q=0.f;
  for (int b=0;b<SB;b++){ s += ps[b*128+c]; q += pq[b*128+c]; }
  float mean = s * (1.0f/NN);
  float var  = q * (1.0f/NN) - mean*mean;
  float inv  = rsqrtf(var + 1e-5f);
  float sc = gamma[c]*inv;
  scale[c]  = sc;
  shiftv[c] = beta[c] - mean*sc;
}

// ---------------- launch ----------------
extern "C" void kernel_launch(void* const* d_in, const int* in_sizes, int n_in,
                              void* d_out, int out_size, void* d_ws, size_t ws_size,
                              hipStream_t stream) {
  const float* x      = (const float*)d_in[0];
  const int*   ei     = (const int*)d_in[1];
  const int*   rows   = ei;
  const int*   cols   = ei + EE;
  const float* W1     = (const float*)d_in[2];
  const float* b1     = (const float*)d_in[3];
  const float* gamma1 = (const float*)d_in[4];
  const float* beta1  = (const float*)d_in[5];
  const float* W2     = (const float*)d_in[6];
  const float* b2     = (const float*)d_in[7];
  const float* W3     = (const float*)d_in[8];
  const float* b3     = (const float*)d_in[9];
  float* out = (float*)d_out;

  char* w = (char*)d_ws;
  float* buf0      = (float*)w; w += (size_t)NN*HN*4;   // hbf (25.6MB) + ebuf (12.9MB), disjoint
  float* buf1      = (float*)w; w += (size_t)NN*HN*4;   // abf bf16
  int*   csr_col   = (int*)w;   w += (size_t)EE*4;
  int*   row_start = (int*)w;   w += (size_t)NN*4;
  int*   cnt       = (int*)w;   w += (size_t)NN*4;
  float* dinv      = (float*)w; w += (size_t)NN*4;
  float* ps        = (float*)w; w += (size_t)SB*128*4;
  float* pq        = (float*)w; w += (size_t)SB*128*4;
  float* scale     = (float*)w; w += 1024;
  float* shiftv    = (float*)w; w += 1024;
  int*   scr0      = (int*)w;   w += 4096;   // pcur[256]
  unsigned short* Wp2 = (unsigned short*)w; w += 128*128*2;
  unsigned short* Wp3 = (unsigned short*)w; w += 128*64*2;
  int* pcur = scr0;
  unsigned* hbf  = (unsigned*)buf0;                 // bf16 h rows (64 uints/row), 25.6 MB
  unsigned* ebuf = (unsigned*)buf0 + (size_t)NN*64; // packed edge slabs, 12.9 MB (disjoint)
  unsigned* abf  = (unsigned*)buf1;                 // bf16 agg rows

  (void)hipMemsetAsync(scr0, 0, 4096, stream);

  const int AB = NN/4, FB = NN/32;

  // bucket || mgemm1 (independent) + W2/W3 pack
  k_fused<<<CB + GB, 256, 0, stream>>>(rows, cols, pcur, ebuf, x, W1, W2, W3, Wp2, Wp3, hbf);
  k_build<<<NBUCK, 256, 0, stream>>>(ebuf, pcur, row_start, cnt, dinv, csr_col);

  // layer 1: agg with per-edge dinv (+b1) -> abf; BN stats
  k_aggd<<<AB, 256, 0, stream>>>(hbf, row_start, cnt, csr_col, dinv, b1, abf);
  k_stats<<<SB, 256, 0, stream>>>(abf, ps, pq);
  k_bnfinal<<<1, 128, 0, stream>>>(ps, pq, gamma1, beta1, scale, shiftv);

  // layer 2: BN+relu staged, @W2, pre-scaled bf16 h2'
  k_mgemm2<<<GB, 256, 0, stream>>>(abf, Wp2, scale, shiftv, dinv, hbf);

  // fused: agg2 + relu + GEMM3 + b3 -> out
  k_aggmm<<<FB, 256, 0, stream>>>(hbf, row_start, cnt, csr_col, dinv, b2, Wp3, b3, out);
}